// Round 8
// baseline (2678.542 us; speedup 1.0000x reference)
//
#include <hip/hip_runtime.h>
#include <hip/hip_fp16.h>

#define NN 50000
#define TT 12
#define EE 800000
#define IN_C 32
#define HID 64
#define OUT_C 32
#define BSZ 64                        // nodes per bucket
#define NB ((NN + BSZ - 1) / BSZ)     // 782
#define CAP 1600                      // slots per (t,bucket); mean 1024, +18 sigma
#define EPB 8192                      // edges per bin block
#define ABLK ((EE + EPB - 1) / EPB)   // 98
#define XPAIRS ((size_t)TT * NN * 16) // half2 elements in x

// ---------------- precompute folded gate matrices ----------------
// Mz = Wz @ Lz_w[:64] (32x64), Bz = bz @ Lz_w[:64] + Lz_b (64); same for h.
__global__ __launch_bounds__(64) void prep_kernel(
    const float* __restrict__ Wz, const float* __restrict__ bz,
    const float* __restrict__ Lzw, const float* __restrict__ Lzb,
    const float* __restrict__ Wh, const float* __restrict__ bh,
    const float* __restrict__ Lhw, const float* __restrict__ Lhb,
    float* __restrict__ Mz, float* __restrict__ Bz,
    float* __restrict__ Mh, float* __restrict__ Bh) {
  const int j = threadIdx.x;
  const int i = blockIdx.x;
  const int h = blockIdx.y;
  const float* W  = h ? Wh  : Wz;
  const float* b  = h ? bh  : bz;
  const float* L  = h ? Lhw : Lzw;
  const float* Lb = h ? Lhb : Lzb;
  float* M = h ? Mh : Mz;
  float* B = h ? Bh : Bz;
  if (i < IN_C) {
    float v = 0.f;
    for (int k = 0; k < HID; ++k) v += W[i * HID + k] * L[k * HID + j];
    M[i * HID + j] = v;
  } else {
    float v = Lb[j];
    for (int k = 0; k < HID; ++k) v += b[k] * L[k * HID + j];
    B[j] = v;
  }
}

// x [T,N,32] fp32 -> fp16 pairs
__global__ __launch_bounds__(256) void xconv_kernel(const float* __restrict__ x,
                                                    __half2* __restrict__ xh) {
  size_t i = (size_t)blockIdx.x * 256 + threadIdx.x;
  if (i < XPAIRS) {
    float2 f = ((const float2*)x)[i];
    xh[i] = __floats2half2_rn(f.x, f.y);
  }
}

// Pass A: bucket-multisplit. Each block: LDS hist of its EPB edges over NB
// buckets, one global atomic per touched bucket grabs a CONTIGUOUS range,
// then places entries {src16 | dstlo6<<16 | w16<<32} bucket-grouped.
__global__ __launch_bounds__(256) void bin_kernel(const int* __restrict__ ei,
                                                  const float* __restrict__ ew,
                                                  int* __restrict__ cursorA,
                                                  unsigned long long* __restrict__ binA,
                                                  int tbase) {
  __shared__ int hist[NB];  // counts, then bases
  __shared__ int rnk[NB];
  int tl = blockIdx.y;
  const int* src = ei + (size_t)(tbase + tl) * 2 * EE;
  const int* dst = src + EE;
  const float* w = ew + (size_t)(tbase + tl) * EE;
  int* cursor = cursorA + (size_t)tl * NB;
  unsigned long long* bin = binA + (size_t)tl * NB * CAP;
  int t = threadIdx.x;
  for (int i = t; i < NB; i += 256) { hist[i] = 0; rnk[i] = 0; }
  __syncthreads();
  int e0 = blockIdx.x * EPB;
#pragma unroll
  for (int i = 0; i < EPB / 256; ++i) {
    int e = e0 + i * 256 + t;
    if (e < EE) atomicAdd(&hist[dst[e] >> 6], 1);
  }
  __syncthreads();
  for (int b = t; b < NB; b += 256)
    hist[b] = atomicAdd(&cursor[b], hist[b]);  // hist becomes this block's base
  __syncthreads();
#pragma unroll
  for (int i = 0; i < EPB / 256; ++i) {
    int e = e0 + i * 256 + t;
    if (e < EE) {
      int d = dst[e], s = src[e];
      int b = d >> 6;
      unsigned short hw = __half_as_ushort(__float2half_rn(w[e]));
      int pos = hist[b] + atomicAdd(&rnk[b], 1);
      if (pos < CAP)
        bin[(size_t)b * CAP + pos] =
            (unsigned long long)((unsigned)s | ((unsigned)(d & 63) << 16)) |
            ((unsigned long long)hw << 32);
    }
  }
}

// per (bucket,t): deg = 1 + sum w over bucket entries (LDS), dinv = rsqrt(deg)
__global__ __launch_bounds__(256) void deg_kernel(const int* __restrict__ cursorA,
                                                  const unsigned long long* __restrict__ binA,
                                                  float* __restrict__ dinvA) {
  __shared__ float wsum[BSZ];
  int tl = blockIdx.y, b = blockIdx.x;
  int t = threadIdx.x;
  if (t < BSZ) wsum[t] = 0.f;
  __syncthreads();
  int cnt = min(cursorA[(size_t)tl * NB + b], CAP);
  const unsigned long long* bin = binA + ((size_t)tl * NB + b) * CAP;
  for (int i = t; i < cnt; i += 256) {
    unsigned long long u = bin[i];
    int dl = (int)((u >> 16) & 63u);
    float wv = __half2float(__ushort_as_half((unsigned short)(u >> 32)));
    atomicAdd(&wsum[dl], wv);
  }
  __syncthreads();
  int n = b * BSZ + t;
  if (t < BSZ && n < NN) dinvA[(size_t)tl * NN + n] = rsqrtf(1.0f + wsum[t]);
}

// Pass B: block per bucket, t-loop inside (keeps all blocks on the same t so
// xh_t stays L2-resident). Scatter edges into column-major LDS y-tile via LDS
// float atomics, normalize + fp32 self-loop, dense gate; acc in registers.
__global__ __launch_bounds__(256) void agg_kernel(
    const float* __restrict__ x, const __half2* __restrict__ xh,
    const float* __restrict__ dinvA, const int* __restrict__ cursorA,
    const unsigned long long* __restrict__ binA,
    const float* __restrict__ Mz, const float* __restrict__ Bz,
    const float* __restrict__ Mh, const float* __restrict__ Bh,
    float* __restrict__ acc, int tbase, int nt) {
  __shared__ float sMz[IN_C * HID], sMh[IN_C * HID], sBz[HID], sBh[HID];
  __shared__ float ytile[IN_C][BSZ];  // [channel][node]
  int t = threadIdx.x;
  for (int i = t; i < IN_C * HID; i += 256) { sMz[i] = Mz[i]; sMh[i] = Mh[i]; }
  if (t < HID) { sBz[t] = Bz[t]; sBh[t] = Bh[t]; }
  int b = blockIdx.x;
  int nbase = b * BSZ;
  int j = t & 63;     // gate column (lane)
  int nl4 = t >> 6;   // wave id 0..3
  float accr[16];
#pragma unroll
  for (int k = 0; k < 16; ++k) accr[k] = 0.f;

  for (int tl = 0; tl < nt; ++tl) {
    __syncthreads();  // previous gate reads / weight staging done
    for (int i = t; i < IN_C * BSZ; i += 256) ((float*)ytile)[i] = 0.f;
    __syncthreads();
    const float* dinv = dinvA + (size_t)tl * NN;
    int cnt = min(cursorA[(size_t)tl * NB + b], CAP);
    const unsigned long long* bin = binA + ((size_t)tl * NB + b) * CAP;
    const __half2* xht = xh + (size_t)(tbase + tl) * NN * 16;
    for (int e = t; e < cnt; e += 256) {
      unsigned long long u = bin[e];
      int s = (int)(u & 0xFFFFu);
      int dl = (int)((u >> 16) & 63u);
      float nm = __half2float(__ushort_as_half((unsigned short)(u >> 32))) * dinv[s];
      // full 64-byte row as four named 16B quads (static indexing only —
      // R7 bug was hp0[c2<8] reading 32B out of a 16B uint4)
      const uint4* xr = (const uint4*)(xht + (size_t)s * 16);
      uint4 q0 = xr[0], q1 = xr[1], q2 = xr[2], q3 = xr[3];
      const __half2* h0 = (const __half2*)&q0;  // channels  0..7
      const __half2* h1 = (const __half2*)&q1;  // channels  8..15
      const __half2* h2 = (const __half2*)&q2;  // channels 16..23
      const __half2* h3 = (const __half2*)&q3;  // channels 24..31
#pragma unroll
      for (int c2 = 0; c2 < 4; ++c2) {
        float2 f = __half22float2(h0[c2]);
        atomicAdd(&ytile[2 * c2][dl], nm * f.x);
        atomicAdd(&ytile[2 * c2 + 1][dl], nm * f.y);
      }
#pragma unroll
      for (int c2 = 0; c2 < 4; ++c2) {
        float2 f = __half22float2(h1[c2]);
        atomicAdd(&ytile[8 + 2 * c2][dl], nm * f.x);
        atomicAdd(&ytile[8 + 2 * c2 + 1][dl], nm * f.y);
      }
#pragma unroll
      for (int c2 = 0; c2 < 4; ++c2) {
        float2 f = __half22float2(h2[c2]);
        atomicAdd(&ytile[16 + 2 * c2][dl], nm * f.x);
        atomicAdd(&ytile[16 + 2 * c2 + 1][dl], nm * f.y);
      }
#pragma unroll
      for (int c2 = 0; c2 < 4; ++c2) {
        float2 f = __half22float2(h3[c2]);
        atomicAdd(&ytile[24 + 2 * c2][dl], nm * f.x);
        atomicAdd(&ytile[24 + 2 * c2 + 1][dl], nm * f.y);
      }
    }
    __syncthreads();
    // normalize + self loop: ytile[c][nl] = dv*(ytile[c][nl] + dv*x[n][c])
    {
      const float* xt = x + (size_t)(tbase + tl) * NN * IN_C;
      int nl = t >> 2;
      int c0 = (t & 3) * 8;
      int n = nbase + nl;
      if (n < NN) {
        float dv = dinv[n];
        const float* xr = xt + (size_t)n * IN_C + c0;
#pragma unroll
        for (int k = 0; k < 8; ++k)
          ytile[c0 + k][nl] = dv * (ytile[c0 + k][nl] + dv * xr[k]);
      }
    }
    __syncthreads();
    // gate: thread covers 16 nodes (node = k*4 + wave) at column j
#pragma unroll
    for (int k = 0; k < 16; ++k) {
      int nl = (k << 2) | nl4;
      int n = nbase + nl;
      if (n < NN) {
        float za = sBz[j], ha = sBh[j];
#pragma unroll
        for (int c = 0; c < IN_C; ++c) {
          float yv = ytile[c][nl];  // broadcast within wave
          za += yv * sMz[c * HID + j];
          ha += yv * sMh[c * HID + j];
        }
        float z = 1.0f / (1.0f + expf(-za));
        accr[k] += (1.0f - z) * tanhf(ha);
      }
    }
  }
#pragma unroll
  for (int k = 0; k < 16; ++k) {
    int nl = (k << 2) | nl4;
    int n = nbase + nl;
    if (n < NN) {
      size_t ai = (size_t)n * HID + j;
      acc[ai] = (tbase == 0 ? 0.f : acc[ai]) + accr[k];
    }
  }
}

// out[n][o] = (acc[n]/T) . W_out[:,o] + b_out[o]
__global__ __launch_bounds__(256) void out_kernel(const float* __restrict__ acc,
                                                  const float* __restrict__ W_out,
                                                  const float* __restrict__ b_out,
                                                  float* __restrict__ out) {
  __shared__ float sW[HID * OUT_C], sB[OUT_C];
  for (int i = threadIdx.x; i < HID * OUT_C; i += 256) sW[i] = W_out[i];
  if (threadIdx.x < OUT_C) sB[threadIdx.x] = b_out[threadIdx.x];
  __syncthreads();
  unsigned tid = blockIdx.x * 256u + threadIdx.x;
  unsigned n = tid >> 5;
  int o = tid & 31;
  if (n >= NN) return;
  const float* ar = acc + (size_t)n * HID;
  float v = 0.f;
#pragma unroll
  for (int k = 0; k < HID; ++k) v += ar[k] * sW[k * OUT_C + o];
  out[(size_t)n * OUT_C + o] = v * (1.0f / (float)TT) + sB[o];
}

static inline char* alignp(char* p, size_t a) {
  return (char*)(((size_t)p + a - 1) & ~(a - 1));
}

extern "C" void kernel_launch(void* const* d_in, const int* in_sizes, int n_in,
                              void* d_out, int out_size, void* d_ws, size_t ws_size,
                              hipStream_t stream) {
  const float* x     = (const float*)d_in[0];  // [T,N,32]
  const int*   ei    = (const int*)d_in[1];    // [T,2,E]
  const float* ew    = (const float*)d_in[2];  // [T,E]
  const float* Wz    = (const float*)d_in[3];
  const float* bz    = (const float*)d_in[4];
  // d_in[5..6] (Wr,br) dead: H==0 so R unused
  const float* Wh    = (const float*)d_in[7];
  const float* bh    = (const float*)d_in[8];
  const float* Lz_w  = (const float*)d_in[9];
  const float* Lz_b  = (const float*)d_in[10];
  // d_in[11..12] (Lr) dead
  const float* Lh_w  = (const float*)d_in[13];
  const float* Lh_b  = (const float*)d_in[14];
  const float* W_out = (const float*)d_in[15];
  const float* b_out = (const float*)d_in[16];
  float* out = (float*)d_out;

  // sizes (bytes)
  const size_t binB  = (size_t)NB * CAP * 8;   // 10.0 MB per t
  const size_t curB  = (size_t)NB * 4;
  const size_t dinvB = (size_t)NN * 4;
  const size_t perT  = binB + curB + dinvB;    // ~10.2 MB
  const size_t xhB   = XPAIRS * 4;             // 38.4 MB
  const size_t fixedB = 4 * ((size_t)2 * IN_C * HID + 2 * HID)
                      + (size_t)NN * HID * 4 + xhB + 4096;  // ~51.3 MB

  int nt = 12;
  if (ws_size < fixedB + 12 * perT) {
    nt = (int)((ws_size - fixedB) / perT);
    if (nt < 1) nt = 1;
    if (nt > 12) nt = 12;
  }

  char* p = (char*)d_ws;
  unsigned long long* bin = (unsigned long long*)p;  // 8-aligned at base
  p += binB * nt;
  int* cursor = (int*)p;  p += curB * nt;
  float* dinv = (float*)p; p += dinvB * nt;
  float* Mz = (float*)p;
  float* Mh = Mz + IN_C * HID;
  float* Bz = Mh + IN_C * HID;
  float* Bh = Bz + HID;
  float* acc = Bh + HID;  // [N,64]
  p = alignp((char*)(acc + (size_t)NN * HID), 256);
  __half2* xh = (__half2*)p;

  prep_kernel<<<dim3(IN_C + 1, 2), 64, 0, stream>>>(Wz, bz, Lz_w, Lz_b, Wh, bh,
                                                    Lh_w, Lh_b, Mz, Bz, Mh, Bh);
  xconv_kernel<<<(unsigned)((XPAIRS + 255) / 256), 256, 0, stream>>>(x, xh);

  for (int tb = 0; tb < TT; tb += nt) {
    int c = (TT - tb < nt) ? (TT - tb) : nt;
    hipMemsetAsync(cursor, 0, curB * c, stream);
    bin_kernel<<<dim3(ABLK, c), 256, 0, stream>>>(ei, ew, cursor, bin, tb);
    deg_kernel<<<dim3(NB, c), 256, 0, stream>>>(cursor, bin, dinv);
    agg_kernel<<<NB, 256, 0, stream>>>(x, xh, dinv, cursor, bin,
                                       Mz, Bz, Mh, Bh, acc, tb, c);
  }

  out_kernel<<<(NN * OUT_C + 255) / 256, 256, 0, stream>>>(acc, W_out, b_out, out);
}

// Round 9
// 1224.294 us; speedup vs baseline: 2.1878x; 2.1878x over previous
//
#include <hip/hip_runtime.h>
#include <hip/hip_fp16.h>

#define NN 50000
#define TT 12
#define EE 800000
#define IN_C 32
#define HID 64
#define OUT_C 32
#define BSZ 64                        // nodes per bucket
#define NB ((NN + BSZ - 1) / BSZ)     // 782
#define CAP 1600                      // slots per (t,bucket); mean 1024
#define EPB 8192                      // edges per bin block
#define ABLK ((EE + EPB - 1) / EPB)   // 98
#define THR 512                       // threads in gather_agg (8 waves)
#define XPAIRS ((size_t)TT * NN * 16) // half2 elements in x

// ---------------- precompute folded gate matrices ----------------
// Mz = Wz @ Lz_w[:64] (32x64), Bz = bz @ Lz_w[:64] + Lz_b (64); same for h.
__global__ __launch_bounds__(64) void prep_kernel(
    const float* __restrict__ Wz, const float* __restrict__ bz,
    const float* __restrict__ Lzw, const float* __restrict__ Lzb,
    const float* __restrict__ Wh, const float* __restrict__ bh,
    const float* __restrict__ Lhw, const float* __restrict__ Lhb,
    float* __restrict__ Mz, float* __restrict__ Bz,
    float* __restrict__ Mh, float* __restrict__ Bh) {
  const int j = threadIdx.x;
  const int i = blockIdx.x;
  const int h = blockIdx.y;
  const float* W  = h ? Wh  : Wz;
  const float* b  = h ? bh  : bz;
  const float* L  = h ? Lhw : Lzw;
  const float* Lb = h ? Lhb : Lzb;
  float* M = h ? Mh : Mz;
  float* B = h ? Bh : Bz;
  if (i < IN_C) {
    float v = 0.f;
    for (int k = 0; k < HID; ++k) v += W[i * HID + k] * L[k * HID + j];
    M[i * HID + j] = v;
  } else {
    float v = Lb[j];
    for (int k = 0; k < HID; ++k) v += b[k] * L[k * HID + j];
    B[j] = v;
  }
}

// x [T,N,32] fp32 -> fp16 pairs
__global__ __launch_bounds__(256) void xconv_kernel(const float* __restrict__ x,
                                                    __half2* __restrict__ xh) {
  size_t i = (size_t)blockIdx.x * 256 + threadIdx.x;
  if (i < XPAIRS) {
    float2 f = ((const float2*)x)[i];
    xh[i] = __floats2half2_rn(f.x, f.y);
  }
}

// Pass A: bucket-multisplit (proven R7/R8). Each block: LDS hist over NB
// buckets, one global atomic per touched bucket grabs a CONTIGUOUS range,
// then places entries {src16 | dstlo6<<16 | w16<<32} bucket-grouped.
__global__ __launch_bounds__(256) void bin_kernel(const int* __restrict__ ei,
                                                  const float* __restrict__ ew,
                                                  int* __restrict__ cursorA,
                                                  unsigned long long* __restrict__ binA,
                                                  int tbase) {
  __shared__ int hist[NB];
  __shared__ int rnk[NB];
  int tl = blockIdx.y;
  const int* src = ei + (size_t)(tbase + tl) * 2 * EE;
  const int* dst = src + EE;
  const float* w = ew + (size_t)(tbase + tl) * EE;
  int* cursor = cursorA + (size_t)tl * NB;
  unsigned long long* bin = binA + (size_t)tl * NB * CAP;
  int t = threadIdx.x;
  for (int i = t; i < NB; i += 256) { hist[i] = 0; rnk[i] = 0; }
  __syncthreads();
  int e0 = blockIdx.x * EPB;
#pragma unroll
  for (int i = 0; i < EPB / 256; ++i) {
    int e = e0 + i * 256 + t;
    if (e < EE) atomicAdd(&hist[dst[e] >> 6], 1);
  }
  __syncthreads();
  for (int b = t; b < NB; b += 256)
    hist[b] = atomicAdd(&cursor[b], hist[b]);  // hist becomes this block's base
  __syncthreads();
#pragma unroll
  for (int i = 0; i < EPB / 256; ++i) {
    int e = e0 + i * 256 + t;
    if (e < EE) {
      int d = dst[e], s = src[e];
      int b = d >> 6;
      unsigned short hw = __half_as_ushort(__float2half_rn(w[e]));
      int pos = hist[b] + atomicAdd(&rnk[b], 1);
      if (pos < CAP)
        bin[(size_t)b * CAP + pos] =
            (unsigned long long)((unsigned)s | ((unsigned)(d & 63) << 16)) |
            ((unsigned long long)hw << 32);
    }
  }
}

// per (bucket,t): deg = 1 + sum w over bucket entries (LDS), dinv = rsqrt(deg)
__global__ __launch_bounds__(256) void deg_kernel(const int* __restrict__ cursorA,
                                                  const unsigned long long* __restrict__ binA,
                                                  float* __restrict__ dinvA) {
  __shared__ float wsum[BSZ];
  int tl = blockIdx.y, b = blockIdx.x;
  int t = threadIdx.x;
  if (t < BSZ) wsum[t] = 0.f;
  __syncthreads();
  int cnt = min(cursorA[(size_t)tl * NB + b], CAP);
  const unsigned long long* bin = binA + ((size_t)tl * NB + b) * CAP;
  for (int i = t; i < cnt; i += 256) {
    unsigned long long u = bin[i];
    int dl = (int)((u >> 16) & 63u);
    float wv = __half2float(__ushort_as_half((unsigned short)(u >> 32)));
    atomicAdd(&wsum[dl], wv);
  }
  __syncthreads();
  int n = b * BSZ + t;
  if (t < BSZ && n < NN) dinvA[(size_t)tl * NN + n] = rsqrtf(1.0f + wsum[t]);
}

// Pass B: block per bucket, t-loop inside (L2-resident xh_t, proven by R8's
// 453 MB FETCH). Per t: in-LDS counting sort of bucket entries by dst-low-6,
// then R6-style wave gather (8 edge-groups x 8 channel-quads) + gate.
// Register acc across all t.  LDS atomics: 2/edge (vs R8's 32/edge).
__global__ __launch_bounds__(THR) void gather_agg_kernel(
    const float* __restrict__ x, const __half2* __restrict__ xh,
    const float* __restrict__ dinvA, const int* __restrict__ cursorA,
    const unsigned long long* __restrict__ binA,
    const float* __restrict__ Mz, const float* __restrict__ Bz,
    const float* __restrict__ Mh, const float* __restrict__ Bh,
    float* __restrict__ acc, int tbase, int nt) {
  __shared__ float sMz[IN_C * HID], sMh[IN_C * HID], sBz[HID], sBh[HID];
  __shared__ unsigned sbuf[CAP];  // sorted {src16 | w16<<16}
  __shared__ int noff[BSZ + 1];   // per-node offsets into sbuf
  __shared__ int plc[BSZ];        // placement cursors
  __shared__ float yt[THR / 64][IN_C];
  int t = threadIdx.x;
  for (int i = t; i < IN_C * HID; i += THR) { sMz[i] = Mz[i]; sMh[i] = Mh[i]; }
  if (t < HID) { sBz[t] = Bz[t]; sBh[t] = Bh[t]; }

  int b = blockIdx.x;
  int nbase = b * BSZ;
  int w = t >> 6;      // wave 0..7
  int lane = t & 63;
  int g = lane >> 3;   // edge group 0..7
  int cc = lane & 7;   // channel quad 0..7 (4 fp16 channels)
  int j = lane;        // gate column
  float accr[BSZ / (THR / 64)];
#pragma unroll
  for (int k = 0; k < BSZ / (THR / 64); ++k) accr[k] = 0.f;

  for (int tl = 0; tl < nt; ++tl) {
    __syncthreads();  // previous iteration's reads of noff/sbuf/yt done
    if (t < BSZ + 1) noff[t] = 0;
    __syncthreads();
    int cnt = min(cursorA[(size_t)tl * NB + b], CAP);
    const unsigned long long* bin = binA + ((size_t)tl * NB + b) * CAP;
    // pass 1: histogram by node-low-6
    for (int e = t; e < cnt; e += THR)
      atomicAdd(&noff[(int)((bin[e] >> 16) & 63u)], 1);
    __syncthreads();
    // serial exclusive scan (64 entries, thread 0)
    if (t == 0) {
      int run = 0;
#pragma unroll
      for (int i = 0; i < BSZ; ++i) {
        int c = noff[i];
        noff[i] = run;
        plc[i] = run;
        run += c;
      }
      noff[BSZ] = run;
    }
    __syncthreads();
    // pass 2: place sorted (bin is L2/L1-hot from pass 1)
    for (int e = t; e < cnt; e += THR) {
      unsigned long long u = bin[e];
      int dl = (int)((u >> 16) & 63u);
      int pos = atomicAdd(&plc[dl], 1);
      sbuf[pos] = (unsigned)(u & 0xFFFFu) | ((unsigned)(u >> 32) << 16);
    }
    __syncthreads();
    // gather + gate: each wave owns 8 nodes (nl = k*8 + w)
    const float* dinv = dinvA + (size_t)tl * NN;
    const __half2* xht = xh + (size_t)(tbase + tl) * NN * 16;
    const float* xt = x + (size_t)(tbase + tl) * NN * IN_C;
#pragma unroll
    for (int k = 0; k < BSZ / (THR / 64); ++k) {
      int nl = (k << 3) | w;
      int n = nbase + nl;
      int e0 = noff[nl], e1 = noff[nl + 1];
      float4 v = {0.f, 0.f, 0.f, 0.f};
      for (int e = e0 + g; e < e1; e += 8) {
        unsigned u = sbuf[e];
        int s = (int)(u & 0xFFFFu);
        float nm = __half2float(__ushort_as_half((unsigned short)(u >> 16))) * dinv[s];
        uint2 xr = ((const uint2*)(xht + (size_t)s * 16))[cc];
        float2 p0 = __half22float2(*(const __half2*)&xr.x);
        float2 p1 = __half22float2(*(const __half2*)&xr.y);
        v.x += nm * p0.x; v.y += nm * p0.y;
        v.z += nm * p1.x; v.w += nm * p1.y;
      }
#pragma unroll
      for (int m = 8; m <= 32; m <<= 1) {
        v.x += __shfl_xor(v.x, m); v.y += __shfl_xor(v.y, m);
        v.z += __shfl_xor(v.z, m); v.w += __shfl_xor(v.w, m);
      }
      if (n < NN) {
        float dv = dinv[n];
        if (g == 0) {  // 8 lanes x float4 = all 32 channels; fp32 self-loop
          float4 xs = ((const float4*)(xt + (size_t)n * IN_C))[cc];
          float4 o;
          o.x = dv * (v.x + dv * xs.x);
          o.y = dv * (v.y + dv * xs.y);
          o.z = dv * (v.z + dv * xs.z);
          o.w = dv * (v.w + dv * xs.w);
          *(float4*)&yt[w][cc * 4] = o;  // wave-private: in-order, no barrier
        }
        float za = sBz[j], ha = sBh[j];
#pragma unroll
        for (int c = 0; c < IN_C; ++c) {
          float yv = yt[w][c];  // wave-broadcast
          za += yv * sMz[c * HID + j];
          ha += yv * sMh[c * HID + j];
        }
        float z = 1.0f / (1.0f + expf(-za));
        accr[k] += (1.0f - z) * tanhf(ha);
      }
    }
  }
#pragma unroll
  for (int k = 0; k < BSZ / (THR / 64); ++k) {
    int n = nbase + ((k << 3) | w);
    if (n < NN) {
      size_t ai = (size_t)n * HID + j;
      acc[ai] = (tbase == 0 ? 0.f : acc[ai]) + accr[k];
    }
  }
}

// out[n][o] = (acc[n]/T) . W_out[:,o] + b_out[o]
__global__ __launch_bounds__(256) void out_kernel(const float* __restrict__ acc,
                                                  const float* __restrict__ W_out,
                                                  const float* __restrict__ b_out,
                                                  float* __restrict__ out) {
  __shared__ float sW[HID * OUT_C], sB[OUT_C];
  for (int i = threadIdx.x; i < HID * OUT_C; i += 256) sW[i] = W_out[i];
  if (threadIdx.x < OUT_C) sB[threadIdx.x] = b_out[threadIdx.x];
  __syncthreads();
  unsigned tid = blockIdx.x * 256u + threadIdx.x;
  unsigned n = tid >> 5;
  int o = tid & 31;
  if (n >= NN) return;
  const float* ar = acc + (size_t)n * HID;
  float v = 0.f;
#pragma unroll
  for (int k = 0; k < HID; ++k) v += ar[k] * sW[k * OUT_C + o];
  out[(size_t)n * OUT_C + o] = v * (1.0f / (float)TT) + sB[o];
}

static inline char* alignp(char* p, size_t a) {
  return (char*)(((size_t)p + a - 1) & ~(a - 1));
}

extern "C" void kernel_launch(void* const* d_in, const int* in_sizes, int n_in,
                              void* d_out, int out_size, void* d_ws, size_t ws_size,
                              hipStream_t stream) {
  const float* x     = (const float*)d_in[0];  // [T,N,32]
  const int*   ei    = (const int*)d_in[1];    // [T,2,E]
  const float* ew    = (const float*)d_in[2];  // [T,E]
  const float* Wz    = (const float*)d_in[3];
  const float* bz    = (const float*)d_in[4];
  // d_in[5..6] (Wr,br) dead: H==0 so R unused
  const float* Wh    = (const float*)d_in[7];
  const float* bh    = (const float*)d_in[8];
  const float* Lz_w  = (const float*)d_in[9];
  const float* Lz_b  = (const float*)d_in[10];
  // d_in[11..12] (Lr) dead
  const float* Lh_w  = (const float*)d_in[13];
  const float* Lh_b  = (const float*)d_in[14];
  const float* W_out = (const float*)d_in[15];
  const float* b_out = (const float*)d_in[16];
  float* out = (float*)d_out;

  // sizes (bytes)
  const size_t binB  = (size_t)NB * CAP * 8;   // 10.0 MB per t
  const size_t curB  = (size_t)NB * 4;
  const size_t dinvB = (size_t)NN * 4;
  const size_t perT  = binB + curB + dinvB;    // ~10.2 MB
  const size_t xhB   = XPAIRS * 4;             // 38.4 MB
  const size_t fixedB = 4 * ((size_t)2 * IN_C * HID + 2 * HID)
                      + (size_t)NN * HID * 4 + xhB + 4096;  // ~51.3 MB

  int nt = 12;
  if (ws_size < fixedB + 12 * perT) {
    nt = (int)((ws_size - fixedB) / perT);
    if (nt < 1) nt = 1;
    if (nt > 12) nt = 12;
  }

  char* p = (char*)d_ws;
  unsigned long long* bin = (unsigned long long*)p;  // 8-aligned at base
  p += binB * nt;
  int* cursor = (int*)p;  p += curB * nt;
  float* dinv = (float*)p; p += dinvB * nt;
  float* Mz = (float*)p;
  float* Mh = Mz + IN_C * HID;
  float* Bz = Mh + IN_C * HID;
  float* Bh = Bz + HID;
  float* acc = Bh + HID;  // [N,64]
  p = alignp((char*)(acc + (size_t)NN * HID), 256);
  __half2* xh = (__half2*)p;

  prep_kernel<<<dim3(IN_C + 1, 2), 64, 0, stream>>>(Wz, bz, Lz_w, Lz_b, Wh, bh,
                                                    Lh_w, Lh_b, Mz, Bz, Mh, Bh);
  xconv_kernel<<<(unsigned)((XPAIRS + 255) / 256), 256, 0, stream>>>(x, xh);

  for (int tb = 0; tb < TT; tb += nt) {
    int c = (TT - tb < nt) ? (TT - tb) : nt;
    hipMemsetAsync(cursor, 0, curB * c, stream);
    bin_kernel<<<dim3(ABLK, c), 256, 0, stream>>>(ei, ew, cursor, bin, tb);
    deg_kernel<<<dim3(NB, c), 256, 0, stream>>>(cursor, bin, dinv);
    gather_agg_kernel<<<NB, THR, 0, stream>>>(x, xh, dinv, cursor, bin,
                                              Mz, Bz, Mh, Bh, acc, tb, c);
  }

  out_kernel<<<(NN * OUT_C + 255) / 256, 256, 0, stream>>>(acc, W_out, b_out, out);
}